// Round 2
// baseline (458.192 us; speedup 1.0000x reference)
//
#include <hip/hip_runtime.h>
#include <stdint.h>

// ---------------------------------------------------------------------------
// DQN hypergraph pipeline, round 6: counted-vmcnt pipelined big_gemm.
//
// r5: 448 us; big_gemm ~55-60 each vs ~26 us memory floor. Limiters:
// __syncthreads() drains vmcnt every K-step (no cross-barrier prefetch) and
// ~110 VALU/thread/K-step of redundant split2 on the B operand.
// Changes:
//  * Tt/Mt produced directly as bf16 hi/lo planes in LDS-tile-ready layout
//    [k/32][c][k%32] by small_fused / reduce_A (bit-identical values).
//  * big_gemm: B staged with global_load_lds (async, no regs/VALU); A
//    reg-staged 2-deep (dual reg sets); triple-buffered LDS; raw s_barrier
//    with counted s_waitcnt vmcnt(N) so loads stay in flight across
//    barriers (T3/T4). A-tile XOR-swizzled ((m>>1)&3 on 16B slots) ->
//    conflict-free writes+reads; B linear (verified conflict-free).
//  * reduce_A widened to 512 blocks.
// Numerics: bit-identical to r5 (same rne1/split2, same MFMA order).
// ---------------------------------------------------------------------------

typedef short short8 __attribute__((ext_vector_type(8)));
typedef float f32x4 __attribute__((ext_vector_type(4)));

static constexpr int N = 8192, E = 4096, F = 128;
static constexpr int SA = 16, SB = 8;  // split-K factors (chunk = 512 both)

#define ASM_VMCNT(n) asm volatile("s_waitcnt vmcnt(" #n ")" ::: "memory")
#define ASM_LGKM0() asm volatile("s_waitcnt lgkmcnt(0)" ::: "memory")

__device__ __forceinline__ void gload_lds16(const short* g, short* l) {
  __builtin_amdgcn_global_load_lds(
      (const __attribute__((address_space(1))) unsigned int*)g,
      (__attribute__((address_space(3))) unsigned int*)l, 16, 0, 0);
}

__device__ __forceinline__ unsigned rotl32(unsigned x, int r) {
  return (x << r) | (x >> (32 - r));
}

__device__ __forceinline__ uint2 threefry2x32(unsigned k0, unsigned k1,
                                              unsigned x0, unsigned x1) {
  unsigned ks[3] = {k0, k1, k0 ^ k1 ^ 0x1BD11BDAu};
  x0 += ks[0];
  x1 += ks[1];
  const int R0[4] = {13, 15, 26, 6};
  const int R1[4] = {17, 29, 16, 24};
#pragma unroll
  for (int i = 0; i < 5; ++i) {
#pragma unroll
    for (int j = 0; j < 4; ++j) {
      const int r = (i % 2 == 0) ? R0[j] : R1[j];
      x0 += x1;
      x1 = rotl32(x1, r);
      x1 ^= x0;
    }
    x0 += ks[(i + 1) % 3];
    x1 += ks[(i + 2) % 3] + (unsigned)(i + 1);
  }
  return make_uint2(x0, x1);
}

// jax partitionable threefry bernoulli: bits = out.x ^ out.y, keep <=> MSB==0
__device__ __forceinline__ float drop_scale(unsigned idx) {
  const uint2 o = threefry2x32(0u, 42u, 0u, idx);
  return ((o.x ^ o.y) & 0x80000000u) ? 0.0f : 2.0f;
}

__device__ __forceinline__ float lrelu(float v) {
  return v >= 0.0f ? v : 0.01f * v;
}

__device__ __forceinline__ unsigned rne1(float a) {  // f32 -> bf16 (low 16)
  unsigned ua = __builtin_bit_cast(unsigned, a);
  ua += 0x7fffu + ((ua >> 16) & 1u);
  return ua >> 16;
}
__device__ __forceinline__ float bf16_val(unsigned u16) {
  return __builtin_bit_cast(float, u16 << 16);
}
__device__ __forceinline__ unsigned pk_bf16(float a, float b) {
  return rne1(a) | (rne1(b) << 16);
}
// hi/lo packed pair for (a,b)
__device__ __forceinline__ void split2(float a, float b, unsigned& hi,
                                       unsigned& lo) {
  const unsigned ha = rne1(a), hb = rne1(b);
  const float ra = a - bf16_val(ha), rb = b - bf16_val(hb);
  hi = ha | (hb << 16);
  lo = rne1(ra) | (rne1(rb) << 16);
}
__device__ __forceinline__ void split1(float a, unsigned& h, unsigned& l) {
  h = rne1(a);
  l = rne1(a - bf16_val(h));
}

// ---------------------------------------------------------------------------
// Big split-K GEMM. 128x128 tile, BK=32, 512 threads = 8 waves (4x2, 32x64
// per wave). Triple-buffered LDS; B planes via global_load_lds; A reg-staged
// 2 tiles ahead; raw barriers + counted vmcnt (loads survive barriers).
// TRANSA=0: A fp32 [M][K] (Hs). TRANSA=1: A fp32 [K][Mfull] (Ht).
// B: bf16 hi/lo planes, tile layout [k/32][c][k%32] (4096 shorts per tile).
// ---------------------------------------------------------------------------
template <bool TRANSA>
__global__ __launch_bounds__(512, 4) void big_gemm(
    const float* __restrict__ A, const short* __restrict__ Bhg,
    const short* __restrict__ Blg, float* __restrict__ P, int M, int lda) {
  __shared__ __align__(16) short As[3][4096];
  __shared__ __align__(16) short Bhs[3][4096];
  __shared__ __align__(16) short Bls[3][4096];

  const int tid = threadIdx.x;
  const int lane = tid & 63;
  const int w = tid >> 6;        // 0..7
  const int wm = (w & 3) << 5;   // 0,32,64,96
  const int wn = (w >> 2) << 6;  // 0,64
  const int l15 = lane & 15;
  const int q = lane >> 4;  // 16B-slot index for fragment reads
  const int r0 = blockIdx.x * 128;
  constexpr int NT = 16;  // kchunk 512 / BK 32
  const int kt0 = blockIdx.y * NT;

  // staging coords
  const int m0a = tid >> 3;          // TRANSA=0 row (first half)
  const int m0b = (512 + tid) >> 3;  // TRANSA=0 row (second half)
  const int kq0 = tid & 7;
  const int m1 = tid & 127;  // TRANSA=1 row
  const int eo1 = tid >> 7;  // TRANSA=1 k-octet

  float Rf[2][8];  // dual A staging sets

  auto loadA = [&](float* R, int kt) {
    if constexpr (!TRANSA) {
      *(float4*)&R[0] =
          *(const float4*)(A + (size_t)(r0 + m0a) * lda + kt * 32 + 4 * kq0);
      *(float4*)&R[4] =
          *(const float4*)(A + (size_t)(r0 + m0b) * lda + kt * 32 + 4 * kq0);
    } else {
#pragma unroll
      for (int r = 0; r < 8; ++r)
        R[r] = A[(size_t)(kt * 32 + 8 * eo1 + r) * lda + r0 + m1];
    }
  };
  auto packA = [&](const float* R, int buf) {
    if constexpr (!TRANSA) {
      const int s0 = (kq0 >> 1) ^ ((m0a >> 1) & 3);
      uint2 u0 = {pk_bf16(R[0], R[1]), pk_bf16(R[2], R[3])};
      *(uint2*)&As[buf][m0a * 32 + s0 * 8 + (kq0 & 1) * 4] = u0;
      const int s1 = (kq0 >> 1) ^ ((m0b >> 1) & 3);
      uint2 u1 = {pk_bf16(R[4], R[5]), pk_bf16(R[6], R[7])};
      *(uint2*)&As[buf][m0b * 32 + s1 * 8 + (kq0 & 1) * 4] = u1;
    } else {
      const int s0 = eo1 ^ ((m1 >> 1) & 3);
      uint4 u = {pk_bf16(R[0], R[1]), pk_bf16(R[2], R[3]),
                 pk_bf16(R[4], R[5]), pk_bf16(R[6], R[7])};
      *(uint4*)&As[buf][m1 * 32 + s0 * 8] = u;
    }
  };
  auto stageB = [&](int buf, int kt) {
    const size_t g = (size_t)kt * 4096 + w * 512 + lane * 8;
    gload_lds16(Bhg + g, &Bhs[buf][w * 512]);
    gload_lds16(Blg + g, &Bls[buf][w * 512]);
  };

  f32x4 acc[2][4];
#pragma unroll
  for (int i = 0; i < 2; ++i)
#pragma unroll
    for (int j = 0; j < 4; ++j) acc[i][j] = (f32x4){0.f, 0.f, 0.f, 0.f};

  // ---- prologue: tiles 0,1 staged; in flight after barrier: A1+B1 ----
  loadA(Rf[0], kt0 + 0);
  stageB(0, kt0 + 0);
  loadA(Rf[1], kt0 + 1);
  stageB(1, kt0 + 1);
  if constexpr (!TRANSA) ASM_VMCNT(4); else ASM_VMCNT(10);
  __builtin_amdgcn_sched_barrier(0);
  packA(Rf[0], 0);
  ASM_LGKM0();
  __builtin_amdgcn_s_barrier();

  auto step = [&](int i, float* Ri, float* Rp) {
    const int cur = i % 3, nxt = (i + 1) % 3, nn = (i + 2) % 3;
    if (i + 2 < NT) {  // issue next-next tile loads (stay in flight)
      loadA(Ri, kt0 + i + 2);
      stageB(nn, kt0 + i + 2);
    }
    __builtin_amdgcn_sched_barrier(0);
    short8 af[2], bh[4], bl[4];
#pragma unroll
    for (int ii = 0; ii < 2; ++ii) {
      const int m = wm + 16 * ii + l15;
      af[ii] = *(const short8*)&As[cur][m * 32 + ((q ^ ((m >> 1) & 3)) << 3)];
    }
#pragma unroll
    for (int j = 0; j < 4; ++j) {
      const int c = wn + 16 * j + l15;
      bh[j] = *(const short8*)&Bhs[cur][c * 32 + (q << 3)];
      bl[j] = *(const short8*)&Bls[cur][c * 32 + (q << 3)];
    }
#pragma unroll
    for (int ii = 0; ii < 2; ++ii)
#pragma unroll
      for (int j = 0; j < 4; ++j) {
        acc[ii][j] = __builtin_amdgcn_mfma_f32_16x16x32_bf16(af[ii], bl[j],
                                                             acc[ii][j], 0, 0, 0);
        acc[ii][j] = __builtin_amdgcn_mfma_f32_16x16x32_bf16(af[ii], bh[j],
                                                             acc[ii][j], 0, 0, 0);
      }
    if (i + 1 < NT) {
      if (i + 2 < NT) {  // drain tile i+1 loads, keep i+2 in flight
        if constexpr (!TRANSA) ASM_VMCNT(4); else ASM_VMCNT(10);
      } else {
        ASM_VMCNT(0);
      }
      __builtin_amdgcn_sched_barrier(0);
      packA(Rp, nxt);
    }
    ASM_LGKM0();
    __builtin_amdgcn_s_barrier();
  };

  for (int ib = 0; ib < NT; ib += 2) {  // unroll x2: static Rf indexing
    step(ib, Rf[0], Rf[1]);
    step(ib + 1, Rf[1], Rf[0]);
  }

  const int s = blockIdx.y;
  const int rquad = q << 2;
#pragma unroll
  for (int i = 0; i < 2; ++i)
#pragma unroll
    for (int j = 0; j < 4; ++j)
#pragma unroll
      for (int r = 0; r < 4; ++r) {
        const int row = r0 + wm + 16 * i + rquad + r;
        const int col = wn + 16 * j + l15;
        P[((size_t)s * M + row) * 128 + col] = acc[i][j][r];
      }
}

// ---------------------------------------------------------------------------
// Fused small GEMMs vs 128x128 weights, K=128, BK=32, both operands hi/lo.
// blockIdx.y==0: Tt planes (hi/lo, tile layout) = (srcT @ Wth)^T.
// blockIdx.y==1: Badd[n][c] = srcB @ Wwt + bias.
// ---------------------------------------------------------------------------
template <bool WA>
__device__ __forceinline__ void small_core(
    const float* __restrict__ src, const float* __restrict__ W,
    const float* __restrict__ bias, float* __restrict__ out,
    short* __restrict__ outH, short* __restrict__ outL, short* WTh, short* WTl,
    short* Xh, short* Xl, int n0, int tid) {
  constexpr int TI = WA ? 4 : 2;
  constexpr int TJ = WA ? 2 : 4;
  const int lane = tid & 63;
  const int w = tid >> 6;
  const int l15 = lane & 15;
  const int wm = (w & 1) * (WA ? 64 : 32);
  const int wn = (w >> 1) * (WA ? 32 : 64);

  f32x4 acc[TI][TJ];
#pragma unroll
  for (int i = 0; i < TI; ++i)
#pragma unroll
    for (int j = 0; j < TJ; ++j) acc[i][j] = (f32x4){0.f, 0.f, 0.f, 0.f};

  for (int k0 = 0; k0 < 128; k0 += 32) {
    // stage W chunk transposed: WT[c][k] = W[k0+k][c], hi/lo
#pragma unroll
    for (int i = 0; i < 2; ++i) {
      const int f = i * 256 + tid;  // 0..511
      const int c = f & 127;
      const int eo = f >> 7;  // 0..3
      uint4 uh, ul;
      unsigned* ph = (unsigned*)&uh;
      unsigned* pl = (unsigned*)&ul;
#pragma unroll
      for (int r = 0; r < 4; ++r) {
        const float a = W[(size_t)(k0 + 8 * eo + 2 * r) * 128 + c];
        const float b = W[(size_t)(k0 + 8 * eo + 2 * r + 1) * 128 + c];
        split2(a, b, ph[r], pl[r]);
      }
      *(uint4*)&WTh[c * 40 + 8 * eo] = uh;
      *(uint4*)&WTl[c * 40 + 8 * eo] = ul;
    }
    // stage src chunk: X[n][k], hi/lo
#pragma unroll
    for (int i = 0; i < 2; ++i) {
      const int qq = i * 256 + tid;  // 0..511
      const int n = qq >> 3;         // 0..63
      const int kq = qq & 7;
      const float4 v =
          *(const float4*)(src + (size_t)(n0 + n) * 128 + k0 + 4 * kq);
      uint2 uh, ul;
      split2(v.x, v.y, uh.x, ul.x);
      split2(v.z, v.w, uh.y, ul.y);
      *(uint2*)&Xh[n * 40 + 4 * kq] = uh;
      *(uint2*)&Xl[n * 40 + 4 * kq] = ul;
    }
    __syncthreads();

    const int koff = (lane >> 4) << 3;
    short8 ah[TI], al[TI], bh[TJ], bl[TJ];
#pragma unroll
    for (int i = 0; i < TI; ++i) {
      const int m = wm + 16 * i + l15;
      ah[i] = WA ? *(const short8*)&WTh[m * 40 + koff]
                 : *(const short8*)&Xh[m * 40 + koff];
      al[i] = WA ? *(const short8*)&WTl[m * 40 + koff]
                 : *(const short8*)&Xl[m * 40 + koff];
    }
#pragma unroll
    for (int j = 0; j < TJ; ++j) {
      const int c = wn + 16 * j + l15;
      bh[j] = WA ? *(const short8*)&Xh[c * 40 + koff]
                 : *(const short8*)&WTh[c * 40 + koff];
      bl[j] = WA ? *(const short8*)&Xl[c * 40 + koff]
                 : *(const short8*)&WTl[c * 40 + koff];
    }
#pragma unroll
    for (int i = 0; i < TI; ++i)
#pragma unroll
      for (int j = 0; j < TJ; ++j) {
        acc[i][j] = __builtin_amdgcn_mfma_f32_16x16x32_bf16(al[i], bh[j],
                                                            acc[i][j], 0, 0, 0);
        acc[i][j] = __builtin_amdgcn_mfma_f32_16x16x32_bf16(ah[i], bl[j],
                                                            acc[i][j], 0, 0, 0);
        acc[i][j] = __builtin_amdgcn_mfma_f32_16x16x32_bf16(ah[i], bh[j],
                                                            acc[i][j], 0, 0, 0);
      }
    __syncthreads();
  }

  const int rquad = (lane >> 4) << 2;
#pragma unroll
  for (int i = 0; i < TI; ++i)
#pragma unroll
    for (int j = 0; j < TJ; ++j) {
      if constexpr (WA) {
        const int colg = n0 + wn + 16 * j + l15;  // n index
        const size_t tb = (size_t)(colg >> 5) * 4096 + (colg & 31);
#pragma unroll
        for (int r = 0; r < 4; ++r) {
          const int row = wm + 16 * i + rquad + r;  // c index
          unsigned h, l;
          split1(acc[i][j][r], h, l);
          outH[tb + (size_t)row * 32] = (short)h;
          outL[tb + (size_t)row * 32] = (short)l;
        }
      } else {
#pragma unroll
        for (int r = 0; r < 4; ++r) {
          const int row = wm + 16 * i + rquad + r;
          const int col = wn + 16 * j + l15;
          out[(size_t)(n0 + row) * 128 + col] = acc[i][j][r] + bias[col];
        }
      }
    }
}

__global__ __launch_bounds__(256) void small_fused(
    const float* __restrict__ srcT, const float* __restrict__ Wth,
    const float* __restrict__ srcB, const float* __restrict__ Wwt,
    const float* __restrict__ bias, short* __restrict__ TtH,
    short* __restrict__ TtL, float* __restrict__ Badd) {
  __shared__ __align__(16) short WTh[128 * 40], WTl[128 * 40];
  __shared__ __align__(16) short Xh[64 * 40], Xl[64 * 40];
  const int n0 = blockIdx.x * 64;
  if (blockIdx.y == 0)  // block-uniform branch; barriers inside are safe
    small_core<true>(srcT, Wth, nullptr, nullptr, TtH, TtL, WTh, WTl, Xh, Xl,
                     n0, threadIdx.x);
  else
    small_core<false>(srcB, Wwt, bias, Badd, nullptr, nullptr, WTh, WTl, Xh, Xl,
                      n0, threadIdx.x);
}

// Mt planes: Mt[c][e] = ew[e] * sum_s P[s][e][c]; tile layout [e/32][c][e%32].
// P [SA][E][128], 8 e-rows per block -> 512 blocks.
__global__ __launch_bounds__(256) void reduce_A(const float* __restrict__ P,
                                                const float* __restrict__ ew,
                                                short* __restrict__ MtH,
                                                short* __restrict__ MtL) {
  __shared__ float Lt[8 * 132];
  const int tid = threadIdx.x;
  const int e0 = blockIdx.x * 8;
  {
    const int el = tid >> 5;  // 0..7
    const int cq = tid & 31;
    float4 a = {0.f, 0.f, 0.f, 0.f};
#pragma unroll
    for (int s = 0; s < SA; ++s) {
      const float4 v =
          *(const float4*)(P + ((size_t)s * E + e0 + el) * 128 + 4 * cq);
      a.x += v.x; a.y += v.y; a.z += v.z; a.w += v.w;
    }
    const float sc = ew[e0 + el];
    a.x *= sc; a.y *= sc; a.z *= sc; a.w *= sc;
    *(float4*)&Lt[el * 132 + 4 * cq] = a;
  }
  __syncthreads();
  {
    const int c = tid >> 1;   // 0..127
    const int eq = tid & 1;   // 0..1
    const int eb = e0 + 4 * eq;
    float4 o;
    o.x = Lt[(4 * eq + 0) * 132 + c];
    o.y = Lt[(4 * eq + 1) * 132 + c];
    o.z = Lt[(4 * eq + 2) * 132 + c];
    o.w = Lt[(4 * eq + 3) * 132 + c];
    uint2 uh, ul;
    split2(o.x, o.y, uh.x, ul.x);
    split2(o.z, o.w, uh.y, ul.y);
    const size_t off = (size_t)(eb >> 5) * 4096 + (size_t)c * 32 + (eb & 31);
    *(uint2*)&MtH[off] = uh;
    *(uint2*)&MtL[off] = ul;
  }
}

// X1[n][c] = dropout(lrelu(sum_s P + Badd));  P [SB][N][128]; bias in Badd
__global__ __launch_bounds__(256) void reduce_B1(const float* __restrict__ P,
                                                 const float* __restrict__ Badd,
                                                 float* __restrict__ X1) {
  const int q = blockIdx.x * 256 + threadIdx.x;
  const int n = q >> 5;
  const int cq = q & 31;
  float4 a = {0.f, 0.f, 0.f, 0.f};
#pragma unroll
  for (int s = 0; s < SB; ++s) {
    const float4 v = *(const float4*)(P + ((size_t)s * N + n) * 128 + 4 * cq);
    a.x += v.x; a.y += v.y; a.z += v.z; a.w += v.w;
  }
  const float4 b = *(const float4*)(Badd + (size_t)n * 128 + 4 * cq);
  const unsigned fb = (unsigned)(n * 128 + 4 * cq);
  float4 o;
  o.x = lrelu(a.x + b.x) * drop_scale(fb + 0u);
  o.y = lrelu(a.y + b.y) * drop_scale(fb + 1u);
  o.z = lrelu(a.z + b.z) * drop_scale(fb + 2u);
  o.w = lrelu(a.w + b.w) * drop_scale(fb + 3u);
  *(float4*)&X1[(size_t)n * 128 + 4 * cq] = o;
}

// out[n] = sum_c lrelu(lrelu(sum_s P + Badd)) * fcw[c]
//          + state[n]*fcw[128] + fcb[0]   (bias folded into Badd)
__global__ __launch_bounds__(256) void reduce_B2(
    const float* __restrict__ P, const float* __restrict__ Badd,
    const float* __restrict__ fcw, const float* __restrict__ state,
    const float* __restrict__ fcb, float* __restrict__ out) {
  __shared__ float part[4];
  const int tid = threadIdx.x;
  const int nn = tid >> 7;
  const int c = tid & 127;
  const int n = blockIdx.x * 2 + nn;
  float v = 0.f;
#pragma unroll
  for (int s = 0; s < SB; ++s) v += P[((size_t)s * N + n) * 128 + c];
  v += Badd[(size_t)n * 128 + c];
  float p = lrelu(lrelu(v)) * fcw[c];
#pragma unroll
  for (int m = 32; m >= 1; m >>= 1) p += __shfl_xor(p, m, 64);
  if ((tid & 63) == 0) part[tid >> 6] = p;
  __syncthreads();
  if (tid < 2)
    out[blockIdx.x * 2 + tid] = part[2 * tid] + part[2 * tid + 1] +
                                state[blockIdx.x * 2 + tid] * fcw[128] + fcb[0];
}

extern "C" void kernel_launch(void* const* d_in, const int* in_sizes, int n_in,
                              void* d_out, int out_size, void* d_ws,
                              size_t ws_size, hipStream_t stream) {
  (void)in_sizes; (void)n_in; (void)out_size; (void)ws_size;

  const float* xi = (const float*)d_in[0];
  const float* x = (const float*)d_in[1];
  const float* Ht = (const float*)d_in[2];   // [E][N]
  const float* Hs = (const float*)d_in[3];   // [E][N]
  const float* state = (const float*)d_in[4];
  const float* wt0 = (const float*)d_in[5];
  const float* th0 = (const float*)d_in[6];
  const float* ew0 = (const float*)d_in[7];
  const float* bi0 = (const float*)d_in[8];
  const float* wt1 = (const float*)d_in[9];
  const float* th1 = (const float*)d_in[10];
  const float* ew1 = (const float*)d_in[11];
  const float* bi1 = (const float*)d_in[12];
  const float* fcw = (const float*)d_in[13];  // [129]
  const float* fcb = (const float*)d_in[14];  // [1]
  float* out = (float*)d_out;                 // [8192]

  // ws layout: P fp32 [8.39M] | Tt hi/lo planes [1M+1M shorts] |
  //            Mt hi/lo planes [512K+512K shorts] | Badd [1M] | X1 [1M]
  float* ws = (float*)d_ws;
  float* P = ws;
  short* TtH = (short*)(P + (size_t)8388608);
  short* TtL = TtH + (size_t)1048576;
  short* MtH = TtL + (size_t)1048576;
  short* MtL = MtH + (size_t)524288;
  float* Badd = (float*)(MtL + (size_t)524288);
  float* X1 = Badd + (size_t)N * 128;

  // ---- layer 1 ----
  small_fused<<<dim3(N / 64, 2), 256, 0, stream>>>(x, th0, xi, wt0, bi0, TtH,
                                                   TtL, Badd);
  big_gemm<false><<<dim3(E / 128, SA), 512, 0, stream>>>(Hs, TtH, TtL, P, E, N);
  reduce_A<<<E / 8, 256, 0, stream>>>(P, ew0, MtH, MtL);
  big_gemm<true><<<dim3(N / 128, SB), 512, 0, stream>>>(Ht, MtH, MtL, P, N, N);
  reduce_B1<<<N * F / 4 / 256, 256, 0, stream>>>(P, Badd, X1);

  // ---- layer 2 + head ----
  small_fused<<<dim3(N / 64, 2), 256, 0, stream>>>(X1, th1, xi, wt1, bi1, TtH,
                                                   TtL, Badd);
  big_gemm<false><<<dim3(E / 128, SA), 512, 0, stream>>>(Hs, TtH, TtL, P, E, N);
  reduce_A<<<E / 8, 256, 0, stream>>>(P, ew1, MtH, MtL);
  big_gemm<true><<<dim3(N / 128, SB), 512, 0, stream>>>(Ht, MtH, MtL, P, N, N);
  reduce_B2<<<N / 2, 256, 0, stream>>>(P, Badd, fcw, state, fcb, out);
}